// Round 16
// baseline (54.995 us; speedup 1.0000x reference)
//
#include <hip/hip_runtime.h>
#include <hip/hip_fp16.h>
#include <math.h>

#define NN 1024
#define CC 200
#define AA 256

static constexpr float P_EXP = 0.8f;
static constexpr float Q_EXP = 2.0f;
static constexpr float EPS_C = 0.01f;

typedef __attribute__((ext_vector_type(8))) _Float16 half8;
typedef __attribute__((ext_vector_type(4))) _Float16 half4v;
typedef __attribute__((ext_vector_type(4))) float f32x4;

// ---------------- prep: W->fp16 (208 rows, zero pad) + counts ----------------
__global__ void k_prep(const float* __restrict__ W, const int* __restrict__ lab,
                       _Float16* __restrict__ Whf, float* __restrict__ accv){
  if (blockIdx.x == 52){
    __shared__ int cnt[CC];
    int t = threadIdx.x;
    for (int i = t; i < CC; i += 256) cnt[i] = 0;
    __syncthreads();
    for (int n = t; n < NN; n += 256) atomicAdd(&cnt[lab[n]], 1);
    __syncthreads();
    for (int i = t; i < CC; i += 256) accv[i] = fmaxf((float)cnt[i], 1.0f);
    return;
  }
  int idx = (blockIdx.x * 256 + threadIdx.x) * 4;
  if (idx >= 208 * AA) return;
  float4 w = make_float4(0.f, 0.f, 0.f, 0.f);
  if (idx < CC * AA) w = *(const float4*)(W + idx);
  Whf[idx + 0] = (_Float16)w.x;
  Whf[idx + 1] = (_Float16)w.y;
  Whf[idx + 2] = (_Float16)w.z;
  Whf[idx + 3] = (_Float16)w.w;
}

// ---------------- DIAGNOSTIC PROBE: max-rate CV stream + L3 warm ----------------
// Classic grid-stride float4 read of all 52.4MB of CV; wave-reduced dummy write.
// Its dispatch counters (dur_us, hbm_gbps) = achievable CV read BW in-harness.
// Side effect: leaves CV L3-resident for k_quad (52MB << 256MB L3).
__global__ __launch_bounds__(256) void k_probe(const float* __restrict__ CV,
                                               float* __restrict__ dst){
  size_t gid    = (size_t)blockIdx.x * 256 + threadIdx.x;
  size_t stride = (size_t)gridDim.x * 256;
  const float4* p = (const float4*)CV;
  const size_t n4 = (size_t)CC * AA * AA / 4;
  float4 acc = make_float4(0.f, 0.f, 0.f, 0.f);
  for (size_t i = gid; i < n4; i += stride){
    float4 v = p[i];
    acc.x += v.x; acc.y += v.y; acc.z += v.z; acc.w += v.w;
  }
  float s = (acc.x + acc.y) + (acc.z + acc.w);
  for (int o = 32; o; o >>= 1) s += __shfl_xor(s, o);
  if ((threadIdx.x & 63) == 0) dst[gid >> 6] = s;
}

// ---------------- quadratic form + shift: one block per l (R9 structure) ----------------
// 200 blocks x 512 thr (8 waves). CV_l (256KB) streamed through 2x16KB LDS
// via global_load_lds (linear dest, source-swizzled), depth-1 + __syncthreads.
// E-frags in regs. MFMA1: M'[a,c] = sum_b CV[a,b]E[c,b]; MFMA2 accumulates
// diag_c( E[c',a](M'[a,c] + 2dm[a]) ). Direct store (no atomics).
__global__ __launch_bounds__(512) void k_quad(
    const _Float16* __restrict__ Whf, const float* __restrict__ CV,
    const float* __restrict__ ms, const float* __restrict__ mtg,
    const float* __restrict__ lamp, float* __restrict__ tbl)
{
  const int l    = blockIdx.x;
  const int tid  = threadIdx.x;
  const int wid  = tid >> 6;
  const int lane = tid & 63;
  const int lrow = lane & 15;
  const int kgrp = lane >> 4;

  __shared__ float4 cvb[2][16][64];     // 2 x 16KB double buffer
  __shared__ _Float16 dmh[AA];          // 2*(mt-ms) fp16

  if (tid < AA)
    dmh[tid] = (_Float16)(2.f * (mtg[l * AA + tid] - ms[l * AA + tid]));

  // ---- E fragments in registers: wave owns ct0 = wid, ct1 = wid+8 ----
  const int ct0 = wid, ct1 = wid + 8;
  half8 ef0[8], ef1[8];
  #pragma unroll
  for (int kt = 0; kt < 8; ++kt){
    half8 wlv = *(const half8*)(Whf + l * AA + kt * 32 + kgrp * 8);
    half8 wc0 = *(const half8*)(Whf + (ct0 * 16 + lrow) * AA + kt * 32 + kgrp * 8);
    ef0[kt] = wc0 - wlv;
    if (wid < 5){
      half8 wc1 = *(const half8*)(Whf + (ct1 * 16 + lrow) * AA + kt * 32 + kgrp * 8);
      ef1[kt] = wc1 - wlv;
    }
  }

  const size_t cvbase = (size_t)l * AA * AA;

  #define STAGE(TILE, BUF) do {                                               \
    _Pragma("unroll")                                                         \
    for (int rr_ = 0; rr_ < 2; ++rr_){                                        \
      int row_ = wid * 2 + rr_;                                               \
      const float* gs_ = CV + cvbase + (size_t)(TILE) * 16 * AA               \
                       + (size_t)row_ * AA + ((lane ^ (row_ & 7)) << 2);      \
      __builtin_amdgcn_global_load_lds(                                       \
        (const __attribute__((address_space(1))) void*)gs_,                   \
        (__attribute__((address_space(3))) void*)&cvb[BUF][row_][0],          \
        16, 0, 0);                                                            \
    }                                                                         \
  } while(0)

  STAGE(0, 0);
  __syncthreads();                       // tile 0 + dmh ready

  f32x4 D2a = {0.f,0.f,0.f,0.f}, D2b = {0.f,0.f,0.f,0.f};
  const float lam = lamp[0];

  for (int t = 0; t < 16; ++t){
    if (t + 1 < 16) STAGE(t + 1, (t + 1) & 1);   // async, overlaps compute

    const int buf = t & 1;
    f32x4 a0 = {0.f,0.f,0.f,0.f}, a1 = {0.f,0.f,0.f,0.f};
    #pragma unroll
    for (int kt = 0; kt < 8; ++kt){
      const int j0 = kt * 8 + kgrp * 2;
      float4 v0 = cvb[buf][lrow][( j0     ) ^ (lrow & 7)];
      float4 v1 = cvb[buf][lrow][( j0 + 1 ) ^ (lrow & 7)];
      half8 cvf;
      cvf[0]=(_Float16)v0.x; cvf[1]=(_Float16)v0.y; cvf[2]=(_Float16)v0.z; cvf[3]=(_Float16)v0.w;
      cvf[4]=(_Float16)v1.x; cvf[5]=(_Float16)v1.y; cvf[6]=(_Float16)v1.z; cvf[7]=(_Float16)v1.w;
      a0 = __builtin_amdgcn_mfma_f32_16x16x32_f16(cvf, ef0[kt], a0, 0, 0, 0);
      if (wid < 5)
        a1 = __builtin_amdgcn_mfma_f32_16x16x32_f16(cvf, ef1[kt], a1, 0, 0, 0);
    }

    half4v dmf = *(const half4v*)&dmh[t * 16 + kgrp * 4];
    half4v wl2 = *(const half4v*)(Whf + l * AA + t * 16 + kgrp * 4);
    {
      half4v wc2 = *(const half4v*)(Whf + (ct0 * 16 + lrow) * AA + t * 16 + kgrp * 4);
      half4v e2  = wc2 - wl2;
      half4v b2;
      b2[0]=(_Float16)a0[0]; b2[1]=(_Float16)a0[1]; b2[2]=(_Float16)a0[2]; b2[3]=(_Float16)a0[3];
      D2a = __builtin_amdgcn_mfma_f32_16x16x16f16(e2, b2,  D2a, 0, 0, 0);
      D2a = __builtin_amdgcn_mfma_f32_16x16x16f16(e2, dmf, D2a, 0, 0, 0);
    }
    if (wid < 5){
      half4v wc2 = *(const half4v*)(Whf + (ct1 * 16 + lrow) * AA + t * 16 + kgrp * 4);
      half4v e2  = wc2 - wl2;
      half4v b2;
      b2[0]=(_Float16)a1[0]; b2[1]=(_Float16)a1[1]; b2[2]=(_Float16)a1[2]; b2[3]=(_Float16)a1[3];
      D2b = __builtin_amdgcn_mfma_f32_16x16x16f16(e2, b2,  D2b, 0, 0, 0);
      D2b = __builtin_amdgcn_mfma_f32_16x16x16f16(e2, dmf, D2b, 0, 0, 0);
    }
    __syncthreads();                     // tile t reads done; t+1 loads drained
  }

  if ((lrow >> 2) == kgrp){
    const int jj = lrow & 3;
    const int c0 = ct0 * 16 + lrow;
    float d0 = (jj == 0) ? D2a[0] : (jj == 1) ? D2a[1] : (jj == 2) ? D2a[2] : D2a[3];
    if (c0 < CC) tbl[l * CC + c0] = 0.5f * lam * d0;
    if (wid < 5){
      const int c1 = ct1 * 16 + lrow;
      float d1 = (jj == 0) ? D2b[0] : (jj == 1) ? D2b[1] : (jj == 2) ? D2b[2] : D2b[3];
      if (c1 < CC) tbl[l * CC + c1] = 0.5f * lam * d1;
    }
  }
  #undef STAGE
}

// ---------------- per-row seesaw loss ----------------
__global__ __launch_bounds__(64) void k_rows(
    const float* __restrict__ ys, const int* __restrict__ lab,
    const float* __restrict__ accv, const float* __restrict__ tbl,
    float* __restrict__ nll)
{
  const int n    = blockIdx.x;
  const int lane = threadIdx.x;
  const int l    = lab[n];
  const float acc_l = accv[l];
  const float log_acc_l = logf(acc_l);

  float z[4];
  float m = -1e30f;
  #pragma unroll
  for (int k = 0; k < 4; k++){
    int cidx = k * 64 + lane;
    float zz = (cidx < CC) ? (ys[n * CC + cidx] + tbl[l * CC + cidx]) : -1e30f;
    z[k] = zz;
    m = fmaxf(m, zz);
  }
  for (int o = 32; o; o >>= 1) m = fmaxf(m, __shfl_xor(m, o));

  float se = 0.f;
  #pragma unroll
  for (int k = 0; k < 4; k++){
    int cidx = k * 64 + lane;
    if (cidx < CC) se += expf(z[k] - m);
  }
  for (int o = 32; o; o >>= 1) se += __shfl_xor(se, o);
  const float L0 = m + logf(se);

  const int kl = l >> 6, ll = l & 63;
  float zsel = (kl == 0) ? z[0] : (kl == 1 ? z[1] : (kl == 2 ? z[2] : z[3]));
  const float zl = __shfl(zsel, ll);
  const float logden = fmaxf(zl - L0, logf(EPS_C));

  float lg[4];
  float m2 = -1e30f;
  #pragma unroll
  for (int k = 0; k < 4; k++){
    int cidx = k * 64 + lane;
    float lz = -1e30f;
    if (cidx < CC){
      lz = z[k];
      if (cidx != l){
        float lratio = (z[k] - L0) - logden;
        float lcomp  = (lratio > 0.f) ? Q_EXP * lratio : 0.f;
        float accc   = accv[cidx];
        float lmit   = (accc < acc_l) ? P_EXP * (logf(accc) - log_acc_l) : 0.f;
        lz += lcomp + lmit;
      }
    }
    lg[k] = lz;
    m2 = fmaxf(m2, lz);
  }
  for (int o = 32; o; o >>= 1) m2 = fmaxf(m2, __shfl_xor(m2, o));
  float se2 = 0.f;
  #pragma unroll
  for (int k = 0; k < 4; k++){
    int cidx = k * 64 + lane;
    if (cidx < CC) se2 += expf(lg[k] - m2);
  }
  for (int o = 32; o; o >>= 1) se2 += __shfl_xor(se2, o);
  const float L1 = m2 + logf(se2);

  if (lane == 0) nll[n] = L1 - zl;
}

// ---------------- mean ----------------
__global__ void k_mean(const float* __restrict__ nll, float* __restrict__ out){
  __shared__ float s[256];
  int t = threadIdx.x;
  float v = 0.f;
  for (int i = t; i < NN; i += 256) v += nll[i];
  s[t] = v; __syncthreads();
  for (int o = 128; o; o >>= 1){ if (t < o) s[t] += s[t + o]; __syncthreads(); }
  if (t == 0) out[0] = s[0] / (float)NN;
}

extern "C" void kernel_launch(void* const* d_in, const int* in_sizes, int n_in,
                              void* d_out, int out_size, void* d_ws, size_t ws_size,
                              hipStream_t stream) {
  const float* W   = (const float*)d_in[0];
  const float* ys  = (const float*)d_in[2];
  const int*   lab = (const int*)  d_in[3];
  const float* lam = (const float*)d_in[4];
  const float* ms  = (const float*)d_in[5];
  const float* mt  = (const float*)d_in[6];
  const float* CV  = (const float*)d_in[7];

  float* ws   = (float*)d_ws;
  float* tbl  = ws;                          // 40000 (fully overwritten)
  float* accv = ws + 40000;                  // 256
  float* nll  = ws + 40256;                  // 1024
  _Float16* Whf = (_Float16*)(ws + 41280);   // 208*256 fp16 (26624 floats)
  float* pdst = ws + 70000;                  // probe scratch (8192 floats)
  float* out  = (float*)d_out;

  k_prep <<<53, 256, 0, stream>>>(W, lab, Whf, accv);
  k_probe<<<2048, 256, 0, stream>>>(CV, pdst);          // BW probe + L3 warm
  k_quad <<<CC, 512, 0, stream>>>(Whf, CV, ms, mt, lam, tbl);
  k_rows <<<NN, 64, 0, stream>>>(ys, lab, accv, tbl, nll);
  k_mean <<<1, 256, 0, stream>>>(nll, out);
}